// Round 8
// baseline (143.212 us; speedup 1.0000x reference)
//
#include <hip/hip_runtime.h>

#define N 8192
#define T 512
#define S 4

__device__ __forceinline__ float dot4(float4 a, float4 b) {
    return a.x*b.x + a.y*b.y + a.z*b.z + a.w*b.w;
}

// lgkm-only barrier: LDS ops drained (cross-wave visibility), but global
// loads stay IN FLIGHT across the barrier (no vmcnt(0) drain).
#define BAR() do {                                          \
    asm volatile("s_waitcnt lgkmcnt(0)" ::: "memory");      \
    __builtin_amdgcn_s_barrier();                           \
    __builtin_amdgcn_sched_barrier(0);                      \
} while (0)

// One block (256 thr, 4 waves) per n.
// Bias phase: thread tid computes b[t] for t=tid and t=256+tid straight from
// registers (no staging LDS, no transpose). Only LDS is the 2 KB b_s used to
// re-layout b for the scan, with a single lgkm-only barrier.
// Scan phase: wave w scans sample s=w (chunk-interleaved weighted prefix scan).
__global__ __launch_bounds__(256) void k_fused(
        const float* __restrict__ drivers,
        const float* __restrict__ cov,
        const float* __restrict__ Y,
        const float* __restrict__ eps,
        const float* __restrict__ tilde_psi,
        const float* __restrict__ gamma_w,
        const float* __restrict__ alpha_w,
        const float* __restrict__ alpha_Y_lag,
        const float* __restrict__ log_tilde_sigma,
        const float* __restrict__ mu_init,
        const float* __restrict__ log_sigma_init,
        float* __restrict__ Zout,
        float* __restrict__ muout,
        float* __restrict__ lvout) {
    __shared__ __align__(16) float b_s[T];           // 2 KB only

    const int tid  = threadIdx.x;
    const int lane = tid & 63;
    const int w    = tid >> 6;        // wave id == sample s
    const int n    = blockIdx.x;

    const float psi    = tilde_psi[0];
    const float lts    = log_tilde_sigma[0];
    const float lsi    = log_sigma_init[0];
    const float sigma  = expf(lts);
    const float sigma0 = expf(lsi);
    const float aY     = alpha_Y_lag[0];
    const float mu0c   = mu_init[0];

    // uniform weights -> scalar loads (SGPRs)
    const float4* g4 = (const float4*)gamma_w;
    const float4* a4 = (const float4*)alpha_w;
    const float4 g0 = g4[0], g1 = g4[1];
    const float4 w0 = a4[0], w1 = a4[1], w2 = a4[2], w3 = a4[3];

    const float4* drv4 = (const float4*)drivers + (size_t)n * 1024;
    const float4* cov4 = (const float4*)cov     + (size_t)n * 2048;
    const float*  Yrow = Y + (size_t)n * T;

    // ---- issue ALL global loads upfront (14 VMEM in flight / thread) ----
    // row t = tid
    const float4 d0a = drv4[2 * tid],        d0b = drv4[2 * tid + 1];
    const float4 c0a = cov4[4 * tid],        c0b = cov4[4 * tid + 1];
    const float4 c0c = cov4[4 * tid + 2],    c0d = cov4[4 * tid + 3];
    const float  y0  = (tid > 0) ? Yrow[tid - 1] : 0.f;
    // row t = 256 + tid
    const float4 d1a = drv4[512 + 2 * tid],  d1b = drv4[512 + 2 * tid + 1];
    const float4 c1a = cov4[1024 + 4 * tid], c1b = cov4[1024 + 4 * tid + 1];
    const float4 c1c = cov4[1024 + 4 * tid + 2], c1d = cov4[1024 + 4 * tid + 3];
    const float  y1  = Yrow[255 + tid];
    // eps for the scan phase
    const size_t chain = ((size_t)w * N + n) * (T / 4);       // float4 units
    const float4* e4 = (const float4*)eps + chain;
    const float4 eA = e4[lane];
    const float4 eB = e4[64 + lane];

    // ---- bias: dots in registers, scalar ds_write to b_s ----
    {
        const float proj0 = dot4(d0a, g0) + dot4(d0b, g1)
                          + dot4(c0a, w0) + dot4(c0b, w1)
                          + dot4(c0c, w2) + dot4(c0d, w3);
        b_s[tid] = (tid == 0) ? (mu0c + proj0) : (proj0 + aY * y0);
        const float proj1 = dot4(d1a, g0) + dot4(d1b, g1)
                          + dot4(c1a, w0) + dot4(c1b, w1)
                          + dot4(c1c, w2) + dot4(c1d, w3);
        b_s[256 + tid] = proj1 + aY * y1;
    }
    BAR();

    // ---- scan phase: wave w handles sample s = w ----
    const float pj1 = psi, pj2 = psi * psi, pj3 = pj2 * psi, pj4 = pj2 * pj2;
    const float wd0 = pj4, wd1 = wd0 * wd0, wd2 = wd1 * wd1,
                wd3 = wd2 * wd2, wd4 = wd3 * wd3, wd5 = wd4 * wd4;
    // p4l = psi^(4*lane)
    float p4l = 1.f;
    {
        float pw = pj4;
        p4l *= (lane & 1)  ? pw : 1.f; pw *= pw;
        p4l *= (lane & 2)  ? pw : 1.f; pw *= pw;
        p4l *= (lane & 4)  ? pw : 1.f; pw *= pw;
        p4l *= (lane & 8)  ? pw : 1.f; pw *= pw;
        p4l *= (lane & 16) ? pw : 1.f; pw *= pw;
        p4l *= (lane & 32) ? pw : 1.f;
    }

    const float4* b_s4 = (const float4*)b_s;
    float4* z4 = (float4*)Zout  + chain;
    float4* m4 = (float4*)muout + chain;
    float4* l4 = (float4*)lvout + chain;
    const float lvv = 2.f * lts;

    float Zlast = 0.f;
    #pragma unroll
    for (int seg = 0; seg < 2; ++seg) {
        const float4 e  = seg ? eB : eA;
        const float4 bq = b_s4[seg * 64 + lane];   // dense b128, conflict-free

        const float sg0 = (seg == 0 && lane == 0) ? sigma0 : sigma;
        // local inclusive scan (from zero state)
        const float z0 = bq.x + sg0 * e.x;
        const float z1 = psi * z0 + (bq.y + sigma * e.y);
        const float z2 = psi * z1 + (bq.z + sigma * e.z);
        const float z3 = psi * z2 + (bq.w + sigma * e.w);

        // wave-level weighted inclusive scan of carries (psi^4 per step)
        float v = z3, up;
        up = __shfl_up(v, 1);  v += (lane >= 1)  ? wd0 * up : 0.f;
        up = __shfl_up(v, 2);  v += (lane >= 2)  ? wd1 * up : 0.f;
        up = __shfl_up(v, 4);  v += (lane >= 4)  ? wd2 * up : 0.f;
        up = __shfl_up(v, 8);  v += (lane >= 8)  ? wd3 * up : 0.f;
        up = __shfl_up(v, 16); v += (lane >= 16) ? wd4 * up : 0.f;
        up = __shfl_up(v, 32); v += (lane >= 32) ? wd5 * up : 0.f;

        float Zprev = __shfl_up(v, 1);
        Zprev = (lane == 0) ? 0.f : Zprev;
        Zprev += p4l * Zlast;                      // bridge from segment A

        const float Z0 = z0 + pj1 * Zprev;
        const float Z1 = z1 + pj2 * Zprev;
        const float Z2 = z2 + pj3 * Zprev;
        const float Z3 = z3 + pj4 * Zprev;

        z4[seg * 64 + lane] = make_float4(Z0, Z1, Z2, Z3);
        m4[seg * 64 + lane] = make_float4(Z0 - sg0 * e.x, Z1 - sigma * e.y,
                                          Z2 - sigma * e.z, Z3 - sigma * e.w);
        l4[seg * 64 + lane] = (seg == 0 && lane == 0)
                            ? make_float4(2.f * lsi, lvv, lvv, lvv)
                            : make_float4(lvv, lvv, lvv, lvv);

        Zlast = __shfl(Z3, 63);                    // Z_255 broadcast
    }
}

extern "C" void kernel_launch(void* const* d_in, const int* in_sizes, int n_in,
                              void* d_out, int out_size, void* d_ws, size_t ws_size,
                              hipStream_t stream) {
    const float* drivers   = (const float*)d_in[0];
    const float* cov       = (const float*)d_in[1];
    const float* Y         = (const float*)d_in[2];
    const float* eps       = (const float*)d_in[3];
    const float* tilde_psi = (const float*)d_in[4];
    const float* gamma_w   = (const float*)d_in[5];
    const float* alpha_w   = (const float*)d_in[6];
    const float* aY        = (const float*)d_in[7];
    const float* lts       = (const float*)d_in[8];
    const float* mu_init   = (const float*)d_in[9];
    const float* lsi       = (const float*)d_in[10];

    float* out   = (float*)d_out;
    const size_t SNT = (size_t)S * N * T;
    float* Zout  = out;
    float* muout = out + SNT;
    float* lvout = out + 2 * SNT;

    k_fused<<<N, 256, 0, stream>>>(drivers, cov, Y, eps, tilde_psi,
                                   gamma_w, alpha_w, aY, lts, mu_init, lsi,
                                   Zout, muout, lvout);
}

// Round 10
// 138.739 us; speedup vs baseline: 1.0322x; 1.0322x over previous
//
#include <hip/hip_runtime.h>

#define N 8192
#define T 512
#define S 4

typedef float fx4 __attribute__((ext_vector_type(4)));

__device__ __forceinline__ float dot4(float4 a, float4 b) {
    return a.x*b.x + a.y*b.y + a.z*b.z + a.w*b.w;
}
__device__ __forceinline__ void nt_store4(float4* p, float4 v) {
    fx4 r; r.x = v.x; r.y = v.y; r.z = v.z; r.w = v.w;
    __builtin_nontemporal_store(r, (fx4*)p);
}

// ---------------- K1: thread-per-t bias, pure sequential streaming ----------
// b[n*T+t] = proj(n,t) + aY*Y[n,t-1] (t>=1);  b[n*T+0] = mu_init + proj.
// Block owns 2048 contiguous ids: drivers 64 KB, cov 128 KB sequential.
__global__ __launch_bounds__(256) void k_bias(
        const float* __restrict__ drivers,
        const float* __restrict__ cov,
        const float* __restrict__ Y,
        const float* __restrict__ gamma_w,
        const float* __restrict__ alpha_w,
        const float* __restrict__ alpha_Y_lag,
        const float* __restrict__ mu_init,
        float* __restrict__ b) {
    const float4* g4 = (const float4*)gamma_w;
    const float4* a4 = (const float4*)alpha_w;
    const float4 g0 = g4[0], g1 = g4[1];
    const float4 w0 = a4[0], w1 = a4[1], w2 = a4[2], w3 = a4[3];
    const float aY   = alpha_Y_lag[0];
    const float mu0c = mu_init[0];

    const size_t base = (size_t)blockIdx.x * 2048 + threadIdx.x;
    const float4* d4 = (const float4*)drivers;
    const float4* c4 = (const float4*)cov;

    #pragma unroll 2
    for (int it = 0; it < 8; ++it) {
        const size_t id = base + (size_t)it * 256;       // id = n*T + t
        float4 dA = d4[id * 2], dB = d4[id * 2 + 1];
        float4 cA = c4[id * 4], cB = c4[id * 4 + 1];
        float4 cC = c4[id * 4 + 2], cD = c4[id * 4 + 3];
        const float yprev = Y[id > 0 ? id - 1 : 0];      // coalesced
        const float proj = dot4(dA, g0) + dot4(dB, g1)
                         + dot4(cA, w0) + dot4(cB, w1)
                         + dot4(cC, w2) + dot4(cD, w3);
        const int t = (int)(id & (T - 1));
        b[id] = (t == 0) ? (mu0c + proj) : (proj + aY * yprev);
    }
}

// ---------------- K2: sample-major wave scan, no LDS, no barriers ----------
// blockIdx = s*(N/4) + g ; wave wv handles chain (s, n = 4g+wv).
// Block streams: eps[s, 4g:4g+4, :] (8 KB seq), b (8 KB, cache-hot),
// Z/mu/lv (3 x 8 KB seq, nontemporal). Long runs across consecutive blocks.
__global__ __launch_bounds__(256) void k_scan(
        const float* __restrict__ bg,
        const float* __restrict__ eps,
        const float* __restrict__ tilde_psi,
        const float* __restrict__ log_tilde_sigma,
        const float* __restrict__ log_sigma_init,
        float* __restrict__ Zout,
        float* __restrict__ muout,
        float* __restrict__ lvout) {
    const int lane = threadIdx.x & 63;
    const int wv   = threadIdx.x >> 6;
    const int s    = blockIdx.x >> 11;            // / (N/4) = 2048
    const int g    = blockIdx.x & 2047;
    const int n    = g * 4 + wv;

    const float psi    = tilde_psi[0];
    const float lts    = log_tilde_sigma[0];
    const float lsi    = log_sigma_init[0];
    const float sigma  = expf(lts);
    const float sigma0 = expf(lsi);
    const float lvv    = 2.f * lts;

    // all global loads upfront
    const size_t chain = ((size_t)s * N + n) * (T / 4);   // float4 units
    const float4* e4 = (const float4*)eps + chain;
    const float4* b4 = (const float4*)bg + (size_t)n * (T / 4);
    const float4 eA = e4[lane],      eB = e4[64 + lane];
    const float4 bA = b4[lane],      bB = b4[64 + lane];

    const float pj1 = psi, pj2 = psi * psi, pj3 = pj2 * psi, pj4 = pj2 * pj2;
    const float wd0 = pj4, wd1 = wd0 * wd0, wd2 = wd1 * wd1,
                wd3 = wd2 * wd2, wd4 = wd3 * wd3, wd5 = wd4 * wd4;
    // p4l = psi^(4*lane)
    float p4l = 1.f;
    {
        float pw = pj4;
        p4l *= (lane & 1)  ? pw : 1.f; pw *= pw;
        p4l *= (lane & 2)  ? pw : 1.f; pw *= pw;
        p4l *= (lane & 4)  ? pw : 1.f; pw *= pw;
        p4l *= (lane & 8)  ? pw : 1.f; pw *= pw;
        p4l *= (lane & 16) ? pw : 1.f; pw *= pw;
        p4l *= (lane & 32) ? pw : 1.f;
    }

    float4* z4 = (float4*)Zout  + chain;
    float4* m4 = (float4*)muout + chain;
    float4* l4 = (float4*)lvout + chain;

    float Zlast = 0.f;
    #pragma unroll
    for (int seg = 0; seg < 2; ++seg) {
        const float4 e  = seg ? eB : eA;
        const float4 bq = seg ? bB : bA;

        const float sg0 = (seg == 0 && lane == 0) ? sigma0 : sigma;
        // local inclusive scan from zero state
        const float z0 = bq.x + sg0 * e.x;
        const float z1 = psi * z0 + (bq.y + sigma * e.y);
        const float z2 = psi * z1 + (bq.z + sigma * e.z);
        const float z3 = psi * z2 + (bq.w + sigma * e.w);

        // wave-level weighted inclusive scan of carries (psi^4 per step)
        float v = z3, up;
        up = __shfl_up(v, 1);  v += (lane >= 1)  ? wd0 * up : 0.f;
        up = __shfl_up(v, 2);  v += (lane >= 2)  ? wd1 * up : 0.f;
        up = __shfl_up(v, 4);  v += (lane >= 4)  ? wd2 * up : 0.f;
        up = __shfl_up(v, 8);  v += (lane >= 8)  ? wd3 * up : 0.f;
        up = __shfl_up(v, 16); v += (lane >= 16) ? wd4 * up : 0.f;
        up = __shfl_up(v, 32); v += (lane >= 32) ? wd5 * up : 0.f;

        float Zprev = __shfl_up(v, 1);
        Zprev = (lane == 0) ? 0.f : Zprev;
        Zprev += p4l * Zlast;                  // bridge from segment A

        const float Z0 = z0 + pj1 * Zprev;
        const float Z1 = z1 + pj2 * Zprev;
        const float Z2 = z2 + pj3 * Zprev;
        const float Z3 = z3 + pj4 * Zprev;

        nt_store4(&z4[seg * 64 + lane], make_float4(Z0, Z1, Z2, Z3));
        nt_store4(&m4[seg * 64 + lane],
                  make_float4(Z0 - sg0 * e.x, Z1 - sigma * e.y,
                              Z2 - sigma * e.z, Z3 - sigma * e.w));
        nt_store4(&l4[seg * 64 + lane],
                  (seg == 0 && lane == 0)
                      ? make_float4(2.f * lsi, lvv, lvv, lvv)
                      : make_float4(lvv, lvv, lvv, lvv));

        Zlast = __shfl(Z3, 63);                // Z_255 broadcast
    }
}

// fallback lv fill (only if ws too small; then b lives in lvout)
__global__ __launch_bounds__(256) void k_lv(
        float* __restrict__ lv,
        const float* __restrict__ lts,
        const float* __restrict__ lsi) {
    int i = blockIdx.x * blockDim.x + threadIdx.x;    // float4 index
    float v = 2.0f * lts[0];
    float4 o = make_float4(v, v, v, v);
    if ((i & (T / 4 - 1)) == 0) o.x = 2.0f * lsi[0];
    ((float4*)lv)[i] = o;
}

extern "C" void kernel_launch(void* const* d_in, const int* in_sizes, int n_in,
                              void* d_out, int out_size, void* d_ws, size_t ws_size,
                              hipStream_t stream) {
    const float* drivers   = (const float*)d_in[0];
    const float* cov       = (const float*)d_in[1];
    const float* Y         = (const float*)d_in[2];
    const float* eps       = (const float*)d_in[3];
    const float* tilde_psi = (const float*)d_in[4];
    const float* gamma_w   = (const float*)d_in[5];
    const float* alpha_w   = (const float*)d_in[6];
    const float* aY        = (const float*)d_in[7];
    const float* lts       = (const float*)d_in[8];
    const float* mu_init   = (const float*)d_in[9];
    const float* lsi       = (const float*)d_in[10];

    float* out   = (float*)d_out;
    const size_t SNT = (size_t)S * N * T;
    float* Zout  = out;
    float* muout = out + SNT;
    float* lvout = out + 2 * SNT;

    const size_t bbytes = (size_t)N * T * sizeof(float);
    const bool ws_ok = (ws_size >= bbytes);
    float* b = ws_ok ? (float*)d_ws : lvout;      // observed ws_size ~1 GiB

    k_bias<<<(N * T) / 2048, 256, 0, stream>>>(drivers, cov, Y, gamma_w,
                                               alpha_w, aY, mu_init, b);
    k_scan<<<S * (N / 4), 256, 0, stream>>>(b, eps, tilde_psi, lts, lsi,
                                            Zout, muout, lvout);
    if (!ws_ok) {
        k_lv<<<(SNT / 4) / 256, 256, 0, stream>>>(lvout, lts, lsi);
    }
}